// Round 7
// baseline (244.230 us; speedup 1.0000x reference)
//
#include <hip/hip_runtime.h>
#include <math.h>

// Problem constants (B=4, S=2048, H=1024, E=16, TOP_K=4)
constexpr int kTokens = 8192;   // B*S
constexpr int kH      = 1024;
constexpr int kE      = 16;
constexpr int kTopK   = 4;
constexpr int kNC     = 16;     // h-splits (64 h each)

// ---------------------------------------------------------------------------
// Stage 1: r0/r6 proven structure, ONE change: __launch_bounds__(256, 8).
// Occupancy math (r6 counters): grid = 8 blocks/CU of work; bounds (256,5)
// capped residency at 5 blocks/CU -> two sequential rounds of block-latency
// L~20us -> 48us makespan at 40% occupancy. LDS is EXACTLY 20480 B and
// 8 x 20480 = 160 KiB = full LDS/CU, VGPR 44 < 64 (the 8-wave/SIMD budget),
// so (256,8) makes the whole grid co-resident: one round, makespan ~ L+ramp.
// Everything else verbatim: 8 passes of [64tok][32h] double-buffered tiles
// (stride 36), depth-1 register prefetch, wave-uniform s_load weights,
// fp32 accum per 16-h chunk -> fp64 fold -> fp64 cross-wave reduce,
// token-major partials store (r6: no fmac cost, best fmac measured).
// ---------------------------------------------------------------------------
__global__ __launch_bounds__(256, 8)
void router_fmac(const float* __restrict__ x,   const float* __restrict__ img,
                 const float* __restrict__ txt, const float* __restrict__ aud,
                 const float* __restrict__ Wg,  const float* __restrict__ Wi,
                 const float* __restrict__ Wt,  const float* __restrict__ Wa,
                 float* __restrict__ partials,  int* __restrict__ ticket)
{
    // 20480 B exactly: two [64][36] tile buffers; reused as red[4][64][20].
    __shared__ float smem[5120];

    const int t  = threadIdx.x;
    const int w  = __builtin_amdgcn_readfirstlane(t >> 6);  // wave id (SGPR)
    const int ln = t & 63;                                  // lane = token
    const int hs    = blockIdx.x & 15;   // h-split
    const int tg    = blockIdx.x >> 4;   // token group
    const int tok0  = tg * 64;
    const int hbase = hs * 64;

    if (blockIdx.x == 0 && t == 0) *ticket = 0;   // reset for fused aux

    const float* Xs[4] = { x,  img, txt, aud };
    const float* Ws[4] = { Wg, Wi,  Wt,  Wa  };

    // staging role: row sr (and sr+32), float4-col sc -> 8 rows x 128 B
    // contiguous per wave-instr (16 lines).
    const int sc = t & 7;
    const int sr = t >> 3;   // 0..31

    // ---- prologue: stage pass 0 (modality 0, s=0) ----
    {
        const float* src = Xs[0] + (size_t)tok0 * kH + hbase + sc * 4;
        const float4 va = *(const float4*)(src + (size_t)sr * kH);
        const float4 vb = *(const float4*)(src + (size_t)(sr + 32) * kH);
        *(float4*)&smem[sr * 36 + sc * 4] = va;
        *(float4*)&smem[(sr + 32) * 36 + sc * 4] = vb;
    }
    __syncthreads();

    double dacc[kE];
#pragma unroll
    for (int e = 0; e < kE; ++e) dacc[e] = 0.0;
    float facc[kE];

#pragma unroll
    for (int p = 0; p < 8; ++p) {        // pass = (modality m = p>>1, half s = p&1)
        const int m = p >> 1;
        const int s = p & 1;

        // prefetch next pass's tile into registers (in flight during compute)
        float4 na, nb;
        if (p < 7) {
            const int m2 = (p + 1) >> 1, s2 = (p + 1) & 1;
            const float* src = Xs[m2] + (size_t)tok0 * kH + hbase + s2 * 32 + sc * 4;
            na = *(const float4*)(src + (size_t)sr * kH);
            nb = *(const float4*)(src + (size_t)(sr + 32) * kH);
        }

        if (s == 0) {
#pragma unroll
            for (int e = 0; e < kE; ++e) facc[e] = 0.f;
        }

        const float* buf   = smem + (p & 1) * 2304;
        const float* wbase = Ws[m] + (size_t)(hbase + s * 32 + w * 8) * kE; // wave-uniform

#pragma unroll
        for (int k4 = 0; k4 < 2; ++k4) {
            const float4 xv = *(const float4*)&buf[ln * 36 + w * 8 + k4 * 4];
#pragma unroll
            for (int j = 0; j < 4; ++j) {
                const float xh = (j == 0) ? xv.x : (j == 1) ? xv.y : (j == 2) ? xv.z : xv.w;
                const float* wr = wbase + (k4 * 4 + j) * kE;   // wave-uniform -> s_load
                const float4 w0 = *(const float4*)(wr + 0);
                const float4 w1 = *(const float4*)(wr + 4);
                const float4 w2 = *(const float4*)(wr + 8);
                const float4 w3 = *(const float4*)(wr + 12);
                facc[0]  += xh * w0.x;  facc[1]  += xh * w0.y;
                facc[2]  += xh * w0.z;  facc[3]  += xh * w0.w;
                facc[4]  += xh * w1.x;  facc[5]  += xh * w1.y;
                facc[6]  += xh * w1.z;  facc[7]  += xh * w1.w;
                facc[8]  += xh * w2.x;  facc[9]  += xh * w2.y;
                facc[10] += xh * w2.z;  facc[11] += xh * w2.w;
                facc[12] += xh * w3.x;  facc[13] += xh * w3.y;
                facc[14] += xh * w3.z;  facc[15] += xh * w3.w;
            }
        }

        if (s == 1) {   // fold 16-h fp32 chunk into fp64
#pragma unroll
            for (int e = 0; e < kE; ++e) dacc[e] += (double)facc[e];
        }

        // write prefetched tile into the other buffer; barrier ends the pass
        if (p < 7) {
            float* nbuf = smem + ((p + 1) & 1) * 2304;
            *(float4*)&nbuf[sr * 36 + sc * 4] = na;
            *(float4*)&nbuf[(sr + 32) * 36 + sc * 4] = nb;
        }
        __syncthreads();
    }

    // ---- cross-wave reduce: red[w][tok][e] (stride 20 floats, 16B-aligned) ----
#pragma unroll
    for (int q = 0; q < 4; ++q) {
        *(float4*)&smem[(w * 64 + ln) * 20 + q * 4] =
            make_float4((float)dacc[q * 4 + 0], (float)dacc[q * 4 + 1],
                        (float)dacc[q * 4 + 2], (float)dacc[q * 4 + 3]);
    }
    __syncthreads();
    {
        const int tok = t >> 2;
        const int eq  = t & 3;
        double s0 = 0.0, s1 = 0.0, s2 = 0.0, s3 = 0.0;
#pragma unroll
        for (int ww = 0; ww < 4; ++ww) {
            const float4 v = *(const float4*)&smem[(ww * 64 + tok) * 20 + eq * 4];
            s0 += (double)v.x;  s1 += (double)v.y;
            s2 += (double)v.z;  s3 += (double)v.w;
        }
        // TOKEN-MAJOR partials [tok][chunk][e].
        *(float4*)&partials[((size_t)(tok0 + tok) * kNC + hs) * kE + eq * 4] =
            make_float4((float)s0, (float)s1, (float)s2, (float)s3);
    }
}

// ---------------------------------------------------------------------------
// Stage 2+3 fused: r5's proven 256-block x 32-token combine/softmax/top-k
// (lowest measured stage-2 cost of any round) + r6's proven last-block aux.
// Thread (tq, eq, hc): sums 8 of the 16 chunk-partials for its e-quad in
// fp64; halves combined deterministically in LDS. Last block (device-scope
// ticket, zeroed by fmac) reduces 256 block-partials -> aux scalar.
// ---------------------------------------------------------------------------
__global__ __launch_bounds__(256)
void router_topk(const float* __restrict__ partials,
                 const float* __restrict__ bg, const float* __restrict__ bi,
                 const float* __restrict__ bt, const float* __restrict__ ba,
                 float* __restrict__ out, float* __restrict__ blocksum,
                 int* __restrict__ ticket)
{
    __shared__ double lgs[32][2][kE + 2];
    __shared__ float  pr[32][kE + 1];
    __shared__ double ps[16][kE];
    __shared__ double fin[kE];
    __shared__ int    sticket;

    const int t    = threadIdx.x;
    const int tq   = t >> 3;        // token 0..31
    const int eq   = (t >> 1) & 3;  // e-quad
    const int hc   = t & 1;         // chunk half (c 0..7 vs 8..15)
    const int tok0 = blockIdx.x * 32;

    double a0 = 0.0, a1 = 0.0, a2 = 0.0, a3 = 0.0;
    if (hc == 0) {  // biases added exactly once, in the low half
        a0 = (double)bg[eq*4+0] + (double)bi[eq*4+0] + (double)bt[eq*4+0] + (double)ba[eq*4+0];
        a1 = (double)bg[eq*4+1] + (double)bi[eq*4+1] + (double)bt[eq*4+1] + (double)ba[eq*4+1];
        a2 = (double)bg[eq*4+2] + (double)bi[eq*4+2] + (double)bt[eq*4+2] + (double)ba[eq*4+2];
        a3 = (double)bg[eq*4+3] + (double)bi[eq*4+3] + (double)bt[eq*4+3] + (double)ba[eq*4+3];
    }

#pragma unroll
    for (int c8 = 0; c8 < 8; ++c8) {
        const int c = hc * 8 + c8;
        const float4 v = *(const float4*)(partials +
            ((size_t)(tok0 + tq) * kNC + c) * kE + eq * 4);
        a0 += (double)v.x;  a1 += (double)v.y;  a2 += (double)v.z;  a3 += (double)v.w;
    }
    lgs[tq][hc][eq*4+0] = a0;  lgs[tq][hc][eq*4+1] = a1;
    lgs[tq][hc][eq*4+2] = a2;  lgs[tq][hc][eq*4+3] = a3;
    __syncthreads();

    if (t < 32) {
        const int tok = tok0 + t;
        double lg[kE];
#pragma unroll
        for (int e = 0; e < kE; ++e) lg[e] = lgs[t][0][e] + lgs[t][1][e];

        double mx = lg[0];
#pragma unroll
        for (int e = 1; e < kE; ++e) mx = fmax(mx, lg[e]);

        float p[kE];
        float sum = 0.f;
#pragma unroll
        for (int e = 0; e < kE; ++e) {
            p[e] = expf((float)(lg[e] - mx));
            sum += p[e];
        }
        const float inv = 1.f / sum;
#pragma unroll
        for (int e = 0; e < kE; ++e) { p[e] *= inv; pr[t][e] = p[e]; }

        // top-4, descending, ties -> smallest index (matches jax.lax.top_k)
        unsigned used = 0;
        float tp[kTopK];
        int   ti[kTopK];
        float s4 = 0.f;
#pragma unroll
        for (int k = 0; k < kTopK; ++k) {
            float best = -1.f;
            int   bidx = 0;
#pragma unroll
            for (int e = 0; e < kE; ++e) {
                if (!((used >> e) & 1u) && p[e] > best) { best = p[e]; bidx = e; }
            }
            used |= 1u << bidx;
            tp[k] = best;
            ti[k] = bidx;
            s4 += best;
        }
        const float rn = 1.f / s4;

        *(float4*)&out[(size_t)tok * kTopK] =
            make_float4((float)ti[0], (float)ti[1], (float)ti[2], (float)ti[3]);
        *(float4*)&out[(size_t)kTokens * kTopK + (size_t)tok * kTopK] =
            make_float4(tp[0] * rn, tp[1] * rn, tp[2] * rn, tp[3] * rn);
    }
    __syncthreads();

    if (t < kE) {
        float s = 0.f;
#pragma unroll
        for (int tk = 0; tk < 32; ++tk) s += pr[tk][t];
        blocksum[blockIdx.x * kE + t] = s;
    }

    // ---- fused aux: last block to arrive reduces all 256 block-partials ----
    __threadfence();                 // make blocksum stores device-visible
    __syncthreads();                 // order all threads' stores before ticket
    if (t == 0) sticket = atomicAdd(ticket, 1);
    __syncthreads();
    if (sticket == (int)gridDim.x - 1) {
        __threadfence();             // acquire side
        const int e  = t & 15;
        const int bq = t >> 4;       // 0..15, 16 blocks each
        double s = 0.0;
#pragma unroll
        for (int k = 0; k < 16; ++k)
            s += (double)((volatile const float*)blocksum)[(bq * 16 + k) * kE + e];
        ps[bq][e] = s;
        __syncthreads();
        if (t < kE) {
            double s2 = 0.0;
#pragma unroll
            for (int q = 0; q < 16; ++q) s2 += ps[q][t];
            fin[t] = s2 / (double)kTokens;
        }
        __syncthreads();
        if (t == 0) {
            double aux = 0.0;
#pragma unroll
            for (int e2 = 0; e2 < kE; ++e2)
                aux += fin[e2] * log(fin[e2] * (double)kE + 1e-9);
            out[(size_t)kTokens * kTopK * 2] = (float)aux;  // element 65536
            *ticket = 0;             // self-reset (fmac re-zeroes anyway)
        }
    }
}

extern "C" void kernel_launch(void* const* d_in, const int* in_sizes, int n_in,
                              void* d_out, int out_size, void* d_ws, size_t ws_size,
                              hipStream_t stream)
{
    const float* x   = (const float*)d_in[0];
    const float* img = (const float*)d_in[1];
    const float* txt = (const float*)d_in[2];
    const float* aud = (const float*)d_in[3];
    const float* Wg  = (const float*)d_in[4];
    const float* bg  = (const float*)d_in[5];
    const float* Wi  = (const float*)d_in[6];
    const float* bi  = (const float*)d_in[7];
    const float* Wt  = (const float*)d_in[8];
    const float* bt  = (const float*)d_in[9];
    const float* Wa  = (const float*)d_in[10];
    const float* ba  = (const float*)d_in[11];

    float* out      = (float*)d_out;
    float* partials = (float*)d_ws;   // [8192][16][16] fp32 = 8 MB
    float* blocksum = (float*)((char*)d_ws + (size_t)kTokens * kNC * kE * 4);  // 16 KB
    int*   ticket   = (int*)((char*)d_ws + (size_t)kTokens * kNC * kE * 4 + 256 * kE * 4);

    router_fmac<<<2048, 256, 0, stream>>>(x, img, txt, aud, Wg, Wi, Wt, Wa, partials, ticket);
    router_topk<<<256, 256, 0, stream>>>(partials, bg, bi, bt, ba, out, blocksum, ticket);
}

// Round 9
// 201.772 us; speedup vs baseline: 1.2104x; 1.2104x over previous
//
#include <hip/hip_runtime.h>
#include <math.h>

// Problem constants (B=4, S=2048, H=1024, E=16, TOP_K=4)
constexpr int kTokens = 8192;   // B*S
constexpr int kH      = 1024;
constexpr int kE      = 16;
constexpr int kTopK   = 4;
constexpr int kNC     = 16;     // h-splits (64 h each)

// ---------------------------------------------------------------------------
// Stage 1 v8 (resubmit -- r8 bench died to broker infra, source audited clean):
// r0/r6 proven structure + EXPERT-SPLIT waves so the register state fits
// __launch_bounds__(256, 8) without spilling.
//
// r7 evidence: (256,8) reached 87% occupancy and 2.24 TB/s -- but the
// 16-expert fp64 accumulator (~70 live VGPRs) forced a spill to scratch
// (VGPR 32, WRITE_SIZE 8MB->114MB, fmac 105us). Fix: wave w = (h-half
// hh = w>>1, expert-half eh = w&1). Each wave: 16 h/pass x 8 experts =
// 128 FMA/lane (unchanged); dacc[8] fp64 (16 VGPR) + facc[8] (8) +
// prefetch (8) ~= 46 live regs <= the 64-cap of 8 waves/SIMD. LDS
// 20480 B x 8 = exactly 160 KiB. Staging, tile layout (stride 36),
// wave-uniform s_load weights (one s_load_dwordx8 per h), fp32-chunk->
// fp64-fold numerics, token-major partials store: identical to proven r6.
// ---------------------------------------------------------------------------
__global__ __launch_bounds__(256, 8)
void router_fmac(const float* __restrict__ x,   const float* __restrict__ img,
                 const float* __restrict__ txt, const float* __restrict__ aud,
                 const float* __restrict__ Wg,  const float* __restrict__ Wi,
                 const float* __restrict__ Wt,  const float* __restrict__ Wa,
                 float* __restrict__ partials,  int* __restrict__ ticket)
{
    // 20480 B exactly: two [64][36] tile buffers; epilogue reuses words
    // 0..3071 as red[4 regions][64 tok][12].
    __shared__ float smem[5120];

    const int t  = threadIdx.x;
    const int w  = __builtin_amdgcn_readfirstlane(t >> 6);  // wave id (SGPR)
    const int hh = w >> 1;   // h-half of the 32-h tile (16 h)
    const int eh = w & 1;    // expert half (8 experts)
    const int ln = t & 63;   // lane = token
    const int hs    = blockIdx.x & 15;   // h-split
    const int tg    = blockIdx.x >> 4;   // token group
    const int tok0  = tg * 64;
    const int hbase = hs * 64;

    if (blockIdx.x == 0 && t == 0) *ticket = 0;   // reset for fused aux

    const float* Xs[4] = { x,  img, txt, aud };
    const float* Ws[4] = { Wg, Wi,  Wt,  Wa  };

    // staging role (unchanged): row sr (and sr+32), float4-col sc
    const int sc = t & 7;
    const int sr = t >> 3;   // 0..31

    // ---- prologue: stage pass 0 (modality 0, s=0) ----
    {
        const float* src = Xs[0] + (size_t)tok0 * kH + hbase + sc * 4;
        const float4 va = *(const float4*)(src + (size_t)sr * kH);
        const float4 vb = *(const float4*)(src + (size_t)(sr + 32) * kH);
        *(float4*)&smem[sr * 36 + sc * 4] = va;
        *(float4*)&smem[(sr + 32) * 36 + sc * 4] = vb;
    }
    __syncthreads();

    double dacc[8];
#pragma unroll
    for (int e = 0; e < 8; ++e) dacc[e] = 0.0;
    float facc[8];

#pragma unroll
    for (int p = 0; p < 8; ++p) {        // pass = (modality m = p>>1, half s = p&1)
        const int m = p >> 1;
        const int s = p & 1;

        // depth-1 register prefetch of next pass's tile (proven structure)
        float4 na, nb;
        if (p < 7) {
            const int m2 = (p + 1) >> 1, s2 = (p + 1) & 1;
            const float* src = Xs[m2] + (size_t)tok0 * kH + hbase + s2 * 32 + sc * 4;
            na = *(const float4*)(src + (size_t)sr * kH);
            nb = *(const float4*)(src + (size_t)(sr + 32) * kH);
        }

        if (s == 0) {
#pragma unroll
            for (int e = 0; e < 8; ++e) facc[e] = 0.f;
        }

        const float* buf   = smem + (p & 1) * 2304;
        // wave-uniform weight base: this wave's 16-h slice, 8-expert half
        const float* wbase = Ws[m] + (size_t)(hbase + s * 32 + hh * 16) * kE + eh * 8;

#pragma unroll
        for (int k4 = 0; k4 < 4; ++k4) {
            const float4 xv = *(const float4*)&buf[ln * 36 + hh * 16 + k4 * 4];
#pragma unroll
            for (int j = 0; j < 4; ++j) {
                const float xh = (j == 0) ? xv.x : (j == 1) ? xv.y : (j == 2) ? xv.z : xv.w;
                const float* wr = wbase + (k4 * 4 + j) * kE;   // wave-uniform -> s_load_dwordx8
                const float4 w0 = *(const float4*)(wr + 0);
                const float4 w1 = *(const float4*)(wr + 4);
                facc[0] += xh * w0.x;  facc[1] += xh * w0.y;
                facc[2] += xh * w0.z;  facc[3] += xh * w0.w;
                facc[4] += xh * w1.x;  facc[5] += xh * w1.y;
                facc[6] += xh * w1.z;  facc[7] += xh * w1.w;
            }
        }

        if (s == 1) {   // fold this modality's 32-h fp32 chunk into fp64
#pragma unroll
            for (int e = 0; e < 8; ++e) dacc[e] += (double)facc[e];
        }

        // write prefetched tile into the other buffer; barrier ends the pass
        if (p < 7) {
            float* nbuf = smem + ((p + 1) & 1) * 2304;
            *(float4*)&nbuf[sr * 36 + sc * 4] = na;
            *(float4*)&nbuf[(sr + 32) * 36 + sc * 4] = nb;
        }
        __syncthreads();
    }

    // ---- cross-wave combine: red[region w][tok][8] (stride 12, 16B-aligned).
    // region = hh*2 + eh = w. Final [tok][e] = sum over hh of the e-half.
    __syncthreads();
#pragma unroll
    for (int q = 0; q < 2; ++q) {
        *(float4*)&smem[(w * 64 + ln) * 12 + q * 4] =
            make_float4((float)dacc[q * 4 + 0], (float)dacc[q * 4 + 1],
                        (float)dacc[q * 4 + 2], (float)dacc[q * 4 + 3]);
    }
    __syncthreads();
    {
        const int tok = t >> 2;
        const int eq  = t & 3;
        const int eh2 = eq >> 1;     // expert half of this e-quad
        const int lq  = eq & 1;      // quad within the half
        const float4 v0 = *(const float4*)&smem[((eh2)     * 64 + tok) * 12 + lq * 4]; // hh=0
        const float4 v1 = *(const float4*)&smem[((2 + eh2) * 64 + tok) * 12 + lq * 4]; // hh=1
        const double s0 = (double)v0.x + (double)v1.x;
        const double s1 = (double)v0.y + (double)v1.y;
        const double s2 = (double)v0.z + (double)v1.z;
        const double s3 = (double)v0.w + (double)v1.w;
        // TOKEN-MAJOR partials [tok][chunk][e]
        *(float4*)&partials[((size_t)(tok0 + tok) * kNC + hs) * kE + eq * 4] =
            make_float4((float)s0, (float)s1, (float)s2, (float)s3);
    }
}

// ---------------------------------------------------------------------------
// Stage 2+3 fused (unchanged from r7, passed on HW): 256 blocks x 32 tokens
// combine + softmax + top-k + per-block expert sums; last block (device-scope
// ticket) reduces the 256 block-partials into the aux-loss scalar.
// ---------------------------------------------------------------------------
__global__ __launch_bounds__(256)
void router_topk(const float* __restrict__ partials,
                 const float* __restrict__ bg, const float* __restrict__ bi,
                 const float* __restrict__ bt, const float* __restrict__ ba,
                 float* __restrict__ out, float* __restrict__ blocksum,
                 int* __restrict__ ticket)
{
    __shared__ double lgs[32][2][kE + 2];
    __shared__ float  pr[32][kE + 1];
    __shared__ double ps[16][kE];
    __shared__ double fin[kE];
    __shared__ int    sticket;

    const int t    = threadIdx.x;
    const int tq   = t >> 3;        // token 0..31
    const int eq   = (t >> 1) & 3;  // e-quad
    const int hc   = t & 1;         // chunk half (c 0..7 vs 8..15)
    const int tok0 = blockIdx.x * 32;

    double a0 = 0.0, a1 = 0.0, a2 = 0.0, a3 = 0.0;
    if (hc == 0) {  // biases added exactly once, in the low half
        a0 = (double)bg[eq*4+0] + (double)bi[eq*4+0] + (double)bt[eq*4+0] + (double)ba[eq*4+0];
        a1 = (double)bg[eq*4+1] + (double)bi[eq*4+1] + (double)bt[eq*4+1] + (double)ba[eq*4+1];
        a2 = (double)bg[eq*4+2] + (double)bi[eq*4+2] + (double)bt[eq*4+2] + (double)ba[eq*4+2];
        a3 = (double)bg[eq*4+3] + (double)bi[eq*4+3] + (double)bt[eq*4+3] + (double)ba[eq*4+3];
    }

#pragma unroll
    for (int c8 = 0; c8 < 8; ++c8) {
        const int c = hc * 8 + c8;
        const float4 v = *(const float4*)(partials +
            ((size_t)(tok0 + tq) * kNC + c) * kE + eq * 4);
        a0 += (double)v.x;  a1 += (double)v.y;  a2 += (double)v.z;  a3 += (double)v.w;
    }
    lgs[tq][hc][eq*4+0] = a0;  lgs[tq][hc][eq*4+1] = a1;
    lgs[tq][hc][eq*4+2] = a2;  lgs[tq][hc][eq*4+3] = a3;
    __syncthreads();

    if (t < 32) {
        const int tok = tok0 + t;
        double lg[kE];
#pragma unroll
        for (int e = 0; e < kE; ++e) lg[e] = lgs[t][0][e] + lgs[t][1][e];

        double mx = lg[0];
#pragma unroll
        for (int e = 1; e < kE; ++e) mx = fmax(mx, lg[e]);

        float p[kE];
        float sum = 0.f;
#pragma unroll
        for (int e = 0; e < kE; ++e) {
            p[e] = expf((float)(lg[e] - mx));
            sum += p[e];
        }
        const float inv = 1.f / sum;
#pragma unroll
        for (int e = 0; e < kE; ++e) { p[e] *= inv; pr[t][e] = p[e]; }

        // top-4, descending, ties -> smallest index (matches jax.lax.top_k)
        unsigned used = 0;
        float tp[kTopK];
        int   ti[kTopK];
        float s4 = 0.f;
#pragma unroll
        for (int k = 0; k < kTopK; ++k) {
            float best = -1.f;
            int   bidx = 0;
#pragma unroll
            for (int e = 0; e < kE; ++e) {
                if (!((used >> e) & 1u) && p[e] > best) { best = p[e]; bidx = e; }
            }
            used |= 1u << bidx;
            tp[k] = best;
            ti[k] = bidx;
            s4 += best;
        }
        const float rn = 1.f / s4;

        *(float4*)&out[(size_t)tok * kTopK] =
            make_float4((float)ti[0], (float)ti[1], (float)ti[2], (float)ti[3]);
        *(float4*)&out[(size_t)kTokens * kTopK + (size_t)tok * kTopK] =
            make_float4(tp[0] * rn, tp[1] * rn, tp[2] * rn, tp[3] * rn);
    }
    __syncthreads();

    if (t < kE) {
        float s = 0.f;
#pragma unroll
        for (int tk = 0; tk < 32; ++tk) s += pr[tk][t];
        blocksum[blockIdx.x * kE + t] = s;
    }

    // ---- fused aux: last block to arrive reduces all 256 block-partials ----
    __threadfence();                 // make blocksum stores device-visible
    __syncthreads();                 // order all threads' stores before ticket
    if (t == 0) sticket = atomicAdd(ticket, 1);
    __syncthreads();
    if (sticket == (int)gridDim.x - 1) {
        __threadfence();             // acquire side
        const int e  = t & 15;
        const int bq = t >> 4;       // 0..15, 16 blocks each
        double s = 0.0;
#pragma unroll
        for (int k = 0; k < 16; ++k)
            s += (double)((volatile const float*)blocksum)[(bq * 16 + k) * kE + e];
        ps[bq][e] = s;
        __syncthreads();
        if (t < kE) {
            double s2 = 0.0;
#pragma unroll
            for (int q = 0; q < 16; ++q) s2 += ps[q][t];
            fin[t] = s2 / (double)kTokens;
        }
        __syncthreads();
        if (t == 0) {
            double aux = 0.0;
#pragma unroll
            for (int e2 = 0; e2 < kE; ++e2)
                aux += fin[e2] * log(fin[e2] * (double)kE + 1e-9);
            out[(size_t)kTokens * kTopK * 2] = (float)aux;  // element 65536
            *ticket = 0;             // self-reset (fmac re-zeroes anyway)
        }
    }
}

extern "C" void kernel_launch(void* const* d_in, const int* in_sizes, int n_in,
                              void* d_out, int out_size, void* d_ws, size_t ws_size,
                              hipStream_t stream)
{
    const float* x   = (const float*)d_in[0];
    const float* img = (const float*)d_in[1];
    const float* txt = (const float*)d_in[2];
    const float* aud = (const float*)d_in[3];
    const float* Wg  = (const float*)d_in[4];
    const float* bg  = (const float*)d_in[5];
    const float* Wi  = (const float*)d_in[6];
    const float* bi  = (const float*)d_in[7];
    const float* Wt  = (const float*)d_in[8];
    const float* bt  = (const float*)d_in[9];
    const float* Wa  = (const float*)d_in[10];
    const float* ba  = (const float*)d_in[11];

    float* out      = (float*)d_out;
    float* partials = (float*)d_ws;   // [8192][16][16] fp32 = 8 MB
    float* blocksum = (float*)((char*)d_ws + (size_t)kTokens * kNC * kE * 4);  // 16 KB
    int*   ticket   = (int*)((char*)d_ws + (size_t)kTokens * kNC * kE * 4 + 256 * kE * 4);

    router_fmac<<<2048, 256, 0, stream>>>(x, img, txt, aud, Wg, Wi, Wt, Wa, partials, ticket);
    router_topk<<<256, 256, 0, stream>>>(partials, bg, bi, bt, ba, out, blocksum, ticket);
}

// Round 10
// 180.304 us; speedup vs baseline: 1.3545x; 1.1191x over previous
//
#include <hip/hip_runtime.h>
#include <math.h>

// Problem constants (B=4, S=2048, H=1024, E=16, TOP_K=4)
constexpr int kTokens = 8192;   // B*S
constexpr int kH      = 1024;
constexpr int kE      = 16;
constexpr int kTopK   = 4;
constexpr int kNC     = 16;     // h-splits (64 h each)

// ---------------------------------------------------------------------------
// Stage 1: r6's fmac VERBATIM (fastest measured: 46.5-48.8us) minus the aux
// ticket. (256,5) bounds, 4 waves x 16 experts, 8 passes of [64tok][32h]
// stride-36 double-buffered tiles, depth-1 register prefetch, wave-uniform
// s_load weights, fp32 chunk -> fp64 fold -> fp64 cross-wave reduce,
// TOKEN-MAJOR partials store. r9 proved occupancy is not binding (40->65%
// at equal dur), so we keep the best-measured configuration unmodified.
// ---------------------------------------------------------------------------
__global__ __launch_bounds__(256, 5)
void router_fmac(const float* __restrict__ x,   const float* __restrict__ img,
                 const float* __restrict__ txt, const float* __restrict__ aud,
                 const float* __restrict__ Wg,  const float* __restrict__ Wi,
                 const float* __restrict__ Wt,  const float* __restrict__ Wa,
                 float* __restrict__ partials)
{
    // 20 KB: two [64][36] tile buffers; reused as red[4][64][20].
    __shared__ float smem[5120];

    const int t  = threadIdx.x;
    const int w  = __builtin_amdgcn_readfirstlane(t >> 6);  // wave id (SGPR)
    const int ln = t & 63;                                  // lane = token
    const int hs    = blockIdx.x & 15;   // h-split
    const int tg    = blockIdx.x >> 4;   // token group
    const int tok0  = tg * 64;
    const int hbase = hs * 64;

    const float* Xs[4] = { x,  img, txt, aud };
    const float* Ws[4] = { Wg, Wi,  Wt,  Wa  };

    // staging role: row sr (and sr+32), float4-col sc
    const int sc = t & 7;
    const int sr = t >> 3;   // 0..31

    // ---- prologue: stage pass 0 (modality 0, s=0) ----
    {
        const float* src = Xs[0] + (size_t)tok0 * kH + hbase + sc * 4;
        const float4 va = *(const float4*)(src + (size_t)sr * kH);
        const float4 vb = *(const float4*)(src + (size_t)(sr + 32) * kH);
        *(float4*)&smem[sr * 36 + sc * 4] = va;
        *(float4*)&smem[(sr + 32) * 36 + sc * 4] = vb;
    }
    __syncthreads();

    double dacc[kE];
#pragma unroll
    for (int e = 0; e < kE; ++e) dacc[e] = 0.0;
    float facc[kE];

#pragma unroll
    for (int p = 0; p < 8; ++p) {        // pass = (modality m = p>>1, half s = p&1)
        const int m = p >> 1;
        const int s = p & 1;

        // prefetch next pass's tile into registers (in flight during compute)
        float4 na, nb;
        if (p < 7) {
            const int m2 = (p + 1) >> 1, s2 = (p + 1) & 1;
            const float* src = Xs[m2] + (size_t)tok0 * kH + hbase + s2 * 32 + sc * 4;
            na = *(const float4*)(src + (size_t)sr * kH);
            nb = *(const float4*)(src + (size_t)(sr + 32) * kH);
        }

        if (s == 0) {
#pragma unroll
            for (int e = 0; e < kE; ++e) facc[e] = 0.f;
        }

        const float* buf   = smem + (p & 1) * 2304;
        const float* wbase = Ws[m] + (size_t)(hbase + s * 32 + w * 8) * kE; // wave-uniform

#pragma unroll
        for (int k4 = 0; k4 < 2; ++k4) {
            const float4 xv = *(const float4*)&buf[ln * 36 + w * 8 + k4 * 4];
#pragma unroll
            for (int j = 0; j < 4; ++j) {
                const float xh = (j == 0) ? xv.x : (j == 1) ? xv.y : (j == 2) ? xv.z : xv.w;
                const float* wr = wbase + (k4 * 4 + j) * kE;   // wave-uniform -> s_load
                const float4 w0 = *(const float4*)(wr + 0);
                const float4 w1 = *(const float4*)(wr + 4);
                const float4 w2 = *(const float4*)(wr + 8);
                const float4 w3 = *(const float4*)(wr + 12);
                facc[0]  += xh * w0.x;  facc[1]  += xh * w0.y;
                facc[2]  += xh * w0.z;  facc[3]  += xh * w0.w;
                facc[4]  += xh * w1.x;  facc[5]  += xh * w1.y;
                facc[6]  += xh * w1.z;  facc[7]  += xh * w1.w;
                facc[8]  += xh * w2.x;  facc[9]  += xh * w2.y;
                facc[10] += xh * w2.z;  facc[11] += xh * w2.w;
                facc[12] += xh * w3.x;  facc[13] += xh * w3.y;
                facc[14] += xh * w3.z;  facc[15] += xh * w3.w;
            }
        }

        if (s == 1) {   // fold 16-h fp32 chunk into fp64
#pragma unroll
            for (int e = 0; e < kE; ++e) dacc[e] += (double)facc[e];
        }

        // write prefetched tile into the other buffer; barrier ends the pass
        if (p < 7) {
            float* nbuf = smem + ((p + 1) & 1) * 2304;
            *(float4*)&nbuf[sr * 36 + sc * 4] = na;
            *(float4*)&nbuf[(sr + 32) * 36 + sc * 4] = nb;
        }
        __syncthreads();
    }

    // ---- cross-wave reduce: red[w][tok][e] (stride 20 floats, 16B-aligned) ----
#pragma unroll
    for (int q = 0; q < 4; ++q) {
        *(float4*)&smem[(w * 64 + ln) * 20 + q * 4] =
            make_float4((float)dacc[q * 4 + 0], (float)dacc[q * 4 + 1],
                        (float)dacc[q * 4 + 2], (float)dacc[q * 4 + 3]);
    }
    __syncthreads();
    {
        const int tok = t >> 2;
        const int eq  = t & 3;
        double s0 = 0.0, s1 = 0.0, s2 = 0.0, s3 = 0.0;
#pragma unroll
        for (int ww = 0; ww < 4; ++ww) {
            const float4 v = *(const float4*)&smem[(ww * 64 + tok) * 20 + eq * 4];
            s0 += (double)v.x;  s1 += (double)v.y;
            s2 += (double)v.z;  s3 += (double)v.w;
        }
        // TOKEN-MAJOR partials [tok][chunk][e].
        *(float4*)&partials[((size_t)(tok0 + tok) * kNC + hs) * kE + eq * 4] =
            make_float4((float)s0, (float)s1, (float)s2, (float)s3);
    }
}

// ---------------------------------------------------------------------------
// Stage 2: r5's topk VERBATIM (best measured "others"): 256 blocks x 32
// tokens, token-major partials reads (each block streams 32 contiguous 1KB
// records), fp64 combine with hc-split halves, softmax/top-k, per-block
// expert sums. NO fence/ticket (r6/r9 proved the fused-aux fence protocol
// costs ~50us of "others").
// ---------------------------------------------------------------------------
__global__ __launch_bounds__(256)
void router_topk(const float* __restrict__ partials,
                 const float* __restrict__ bg, const float* __restrict__ bi,
                 const float* __restrict__ bt, const float* __restrict__ ba,
                 float* __restrict__ out, float* __restrict__ blocksum)
{
    __shared__ double lgs[32][2][kE + 2];
    __shared__ float  pr[32][kE + 1];

    const int t    = threadIdx.x;
    const int tq   = t >> 3;        // token 0..31
    const int eq   = (t >> 1) & 3;  // e-quad
    const int hc   = t & 1;         // chunk half (c 0..7 vs 8..15)
    const int tok0 = blockIdx.x * 32;

    double a0 = 0.0, a1 = 0.0, a2 = 0.0, a3 = 0.0;
    if (hc == 0) {  // biases added exactly once, in the low half
        a0 = (double)bg[eq*4+0] + (double)bi[eq*4+0] + (double)bt[eq*4+0] + (double)ba[eq*4+0];
        a1 = (double)bg[eq*4+1] + (double)bi[eq*4+1] + (double)bt[eq*4+1] + (double)ba[eq*4+1];
        a2 = (double)bg[eq*4+2] + (double)bi[eq*4+2] + (double)bt[eq*4+2] + (double)ba[eq*4+2];
        a3 = (double)bg[eq*4+3] + (double)bi[eq*4+3] + (double)bt[eq*4+3] + (double)ba[eq*4+3];
    }

#pragma unroll
    for (int c8 = 0; c8 < 8; ++c8) {
        const int c = hc * 8 + c8;
        const float4 v = *(const float4*)(partials +
            ((size_t)(tok0 + tq) * kNC + c) * kE + eq * 4);
        a0 += (double)v.x;  a1 += (double)v.y;  a2 += (double)v.z;  a3 += (double)v.w;
    }
    lgs[tq][hc][eq*4+0] = a0;  lgs[tq][hc][eq*4+1] = a1;
    lgs[tq][hc][eq*4+2] = a2;  lgs[tq][hc][eq*4+3] = a3;
    __syncthreads();

    if (t < 32) {
        const int tok = tok0 + t;
        double lg[kE];
#pragma unroll
        for (int e = 0; e < kE; ++e) lg[e] = lgs[t][0][e] + lgs[t][1][e];

        double mx = lg[0];
#pragma unroll
        for (int e = 1; e < kE; ++e) mx = fmax(mx, lg[e]);

        float p[kE];
        float sum = 0.f;
#pragma unroll
        for (int e = 0; e < kE; ++e) {
            p[e] = expf((float)(lg[e] - mx));
            sum += p[e];
        }
        const float inv = 1.f / sum;
#pragma unroll
        for (int e = 0; e < kE; ++e) { p[e] *= inv; pr[t][e] = p[e]; }

        // top-4, descending, ties -> smallest index (matches jax.lax.top_k)
        unsigned used = 0;
        float tp[kTopK];
        int   ti[kTopK];
        float s4 = 0.f;
#pragma unroll
        for (int k = 0; k < kTopK; ++k) {
            float best = -1.f;
            int   bidx = 0;
#pragma unroll
            for (int e = 0; e < kE; ++e) {
                if (!((used >> e) & 1u) && p[e] > best) { best = p[e]; bidx = e; }
            }
            used |= 1u << bidx;
            tp[k] = best;
            ti[k] = bidx;
            s4 += best;
        }
        const float rn = 1.f / s4;

        *(float4*)&out[(size_t)tok * kTopK] =
            make_float4((float)ti[0], (float)ti[1], (float)ti[2], (float)ti[3]);
        *(float4*)&out[(size_t)kTokens * kTopK + (size_t)tok * kTopK] =
            make_float4(tp[0] * rn, tp[1] * rn, tp[2] * rn, tp[3] * rn);
    }
    __syncthreads();

    if (t < kE) {
        float s = 0.f;
#pragma unroll
        for (int tk = 0; tk < 32; ++tk) s += pr[tk][t];
        blocksum[blockIdx.x * kE + t] = s;
    }
}

// ---------------------------------------------------------------------------
// Stage 3: r5's aux VERBATIM: 256 block-partials -> mean prob per expert ->
// aux loss scalar. 256 threads x 16 coalesced loads + fp64 LDS tree.
// ---------------------------------------------------------------------------
__global__ __launch_bounds__(256)
void router_aux(const float* __restrict__ blocksum, float* __restrict__ out)
{
    __shared__ double ps[16][kE];
    __shared__ double fin[kE];
    const int t = threadIdx.x;
    {
        const int e  = t & 15;
        const int bq = t >> 4;   // 0..15
        double s = 0.0;
#pragma unroll
        for (int k = 0; k < 16; ++k)
            s += (double)blocksum[(bq * 16 + k) * kE + e];
        ps[bq][e] = s;
    }
    __syncthreads();
    if (t < kE) {
        double s = 0.0;
#pragma unroll
        for (int q = 0; q < 16; ++q) s += ps[q][t];
        fin[t] = s / (double)kTokens;
    }
    __syncthreads();
    if (t == 0) {
        double aux = 0.0;
#pragma unroll
        for (int e = 0; e < kE; ++e) aux += ps[0][e] * 0.0 + fin[e] * log(fin[e] * (double)kE + 1e-9);
        out[(size_t)kTokens * kTopK * 2] = (float)aux;  // element 65536
    }
}

extern "C" void kernel_launch(void* const* d_in, const int* in_sizes, int n_in,
                              void* d_out, int out_size, void* d_ws, size_t ws_size,
                              hipStream_t stream)
{
    const float* x   = (const float*)d_in[0];
    const float* img = (const float*)d_in[1];
    const float* txt = (const float*)d_in[2];
    const float* aud = (const float*)d_in[3];
    const float* Wg  = (const float*)d_in[4];
    const float* bg  = (const float*)d_in[5];
    const float* Wi  = (const float*)d_in[6];
    const float* bi  = (const float*)d_in[7];
    const float* Wt  = (const float*)d_in[8];
    const float* bt  = (const float*)d_in[9];
    const float* Wa  = (const float*)d_in[10];
    const float* ba  = (const float*)d_in[11];

    float* out      = (float*)d_out;
    float* partials = (float*)d_ws;   // [8192][16][16] fp32 = 8 MB
    float* blocksum = (float*)((char*)d_ws + (size_t)kTokens * kNC * kE * 4);  // 16 KB

    router_fmac<<<2048, 256, 0, stream>>>(x, img, txt, aud, Wg, Wi, Wt, Wa, partials);
    router_topk<<<256, 256, 0, stream>>>(partials, bg, bi, bt, ba, out, blocksum);
    router_aux<<<1, 256, 0, stream>>>(blocksum, out);
}